// Round 22
// baseline (81.502 us; speedup 1.0000x reference)
//
#include <hip/hip_runtime.h>
#include <math.h>

namespace {
constexpr int S  = 256;
constexpr int NT = 256;
constexpr float SCALE = 0.0625f;  // 1/sqrt(256)
constexpr int KLD = 264;          // qkt LDS row stride (f16): 256 + 8 pad
}

typedef _Float16 f16x4 __attribute__((ext_vector_type(4)));
typedef _Float16 f16x8 __attribute__((ext_vector_type(8)));
typedef float    f32x4 __attribute__((ext_vector_type(4)));

#define MFMA(a, b, c) __builtin_amdgcn_mfma_f32_16x16x32_f16((a), (b), (c), 0, 0, 0)

// ===== prep: fused {qkt 64s x 64t (2-half reg-staged K), vsplit} — %3 roles =====
// All splits are 2-way fp16 (hi/lo: 22 mantissa bits ~ fp32).
// packed r idx = sb*4096 + tcg*512 + lane*8 + e
__global__ __launch_bounds__(NT, 4) void prep_kernel(
    const float* __restrict__ q, const float* __restrict__ k,
    const float* __restrict__ v,
    _Float16* __restrict__ vth, _Float16* __restrict__ vtl,
    _Float16* __restrict__ r_hi, _Float16* __restrict__ r_lo,
    int nbh, int swzq)
{
    __shared__ __align__(16) unsigned char lds_arena[32 * KLD * 2 * 2];  // 33.8 KB

    const int tid  = threadIdx.x;
    const int trio = blockIdx.x / 3;
    const int role = blockIdx.x % 3;

    if (role < 2) {
        // ===== QKT role: 64s x 64t, K staged in 2 halves FROM REGISTERS =====
        _Float16* kh = (_Float16*)lds_arena;         // 32 x KLD
        _Float16* kl = kh + 32 * KLD;

        const int w = tid >> 6, l = tid & 63, l15 = l & 15, l4 = l >> 4;

        int L = trio * 2 + role;                 // [0, nbh*16)
        if (swzq) {
            const int n = nbh * 16;
            L = (L & 7) * (n >> 3) + (L >> 3);
        }
        const int bh = L >> 4;
        const int s0 = ((L >> 2) & 3) << 6;
        const int t0 = (L & 3) << 6;

        const float* qb = q + ((size_t)bh << 16);
        const float* kb = k + ((size_t)bh << 16);
        const float* ksrc = kb + (size_t)t0 * S;    // 64 KB contiguous

        // hoist: issue K half-0 loads + all Q loads back-to-back
        float4 kf0[8];
        #pragma unroll
        for (int it = 0; it < 8; ++it)
            kf0[it] = *(const float4*)&ksrc[it * 1024 + tid * 4];

        f16x8 qh[8], ql[8];
        {
            const float* qr = qb + (size_t)(s0 + 16 * w + l15) * S;
            float4 qf[16];
            #pragma unroll
            for (int kc = 0; kc < 8; ++kc) {
                qf[2 * kc]     = *(const float4*)&qr[kc * 32 + l4 * 8];
                qf[2 * kc + 1] = *(const float4*)&qr[kc * 32 + l4 * 8 + 4];
            }
            #pragma unroll
            for (int kc = 0; kc < 8; ++kc) {
                const float xs[8] = {qf[2*kc].x, qf[2*kc].y, qf[2*kc].z, qf[2*kc].w,
                                     qf[2*kc+1].x, qf[2*kc+1].y, qf[2*kc+1].z, qf[2*kc+1].w};
                f16x8 hv, lv;
                #pragma unroll
                for (int e = 0; e < 8; ++e) {
                    const float x = xs[e] * SCALE;
                    const _Float16 hi = (_Float16)x;
                    hv[e] = hi; lv[e] = (_Float16)(x - (float)hi);
                }
                qh[kc] = hv; ql[kc] = lv;
            }
        }

        // write half 0 (t-rows [t0, t0+32)) from registers
        #pragma unroll
        for (int it = 0; it < 8; ++it) {
            const int idx = it * 1024 + tid * 4;
            const float xs[4] = {kf0[it].x, kf0[it].y, kf0[it].z, kf0[it].w};
            f16x4 hv, lv;
            #pragma unroll
            for (int e = 0; e < 4; ++e) {
                const _Float16 hi = (_Float16)xs[e];
                hv[e] = hi; lv[e] = (_Float16)(xs[e] - (float)hi);
            }
            const int row = idx >> 8;
            const int col = idx & 255;
            *(f16x4*)&kh[row * KLD + col] = hv;
            *(f16x4*)&kl[row * KLD + col] = lv;
        }
        // issue half-1 loads; they fly under MFMA half-0
        float4 kf1[8];
        #pragma unroll
        for (int it = 0; it < 8; ++it)
            kf1[it] = *(const float4*)&ksrc[8192 + it * 1024 + tid * 4];
        __syncthreads();

        f32x4 acc[4];
        #pragma unroll
        for (int j = 0; j < 4; ++j) acc[j] = (f32x4){0.f, 0.f, 0.f, 0.f};

        #pragma unroll
        for (int kc = 0; kc < 8; ++kc) {
            #pragma unroll
            for (int jl = 0; jl < 2; ++jl) {
                const int bo = (jl * 16 + l15) * KLD + kc * 32 + l4 * 8;
                const f16x8 khf = *(const f16x8*)&kh[bo];
                const f16x8 klf = *(const f16x8*)&kl[bo];
                acc[jl] = MFMA(qh[kc], khf, acc[jl]);
                acc[jl] = MFMA(qh[kc], klf, acc[jl]);
                acc[jl] = MFMA(ql[kc], khf, acc[jl]);
            }
        }
        __syncthreads();   // half-0 reads complete

        // write half 1 (t-rows [t0+32, t0+64)) from registers
        #pragma unroll
        for (int it = 0; it < 8; ++it) {
            const int idx = it * 1024 + tid * 4;
            const float xs[4] = {kf1[it].x, kf1[it].y, kf1[it].z, kf1[it].w};
            f16x4 hv, lv;
            #pragma unroll
            for (int e = 0; e < 4; ++e) {
                const _Float16 hi = (_Float16)xs[e];
                hv[e] = hi; lv[e] = (_Float16)(xs[e] - (float)hi);
            }
            const int row = idx >> 8;
            const int col = idx & 255;
            *(f16x4*)&kh[row * KLD + col] = hv;
            *(f16x4*)&kl[row * KLD + col] = lv;
        }
        __syncthreads();

        #pragma unroll
        for (int kc = 0; kc < 8; ++kc) {
            #pragma unroll
            for (int jl = 0; jl < 2; ++jl) {
                const int bo = (jl * 16 + l15) * KLD + kc * 32 + l4 * 8;
                const f16x8 khf = *(const f16x8*)&kh[bo];
                const f16x8 klf = *(const f16x8*)&kl[bo];
                acc[2 + jl] = MFMA(qh[kc], khf, acc[2 + jl]);
                acc[2 + jl] = MFMA(qh[kc], klf, acc[2 + jl]);
                acc[2 + jl] = MFMA(ql[kc], khf, acc[2 + jl]);
            }
        }
        __syncthreads();   // all waves done with kh/kl -> reuse kh as bounce

        // ---- packed epilogue via per-wave LDS bounce (4 KB/wave in kh) ----
        _Float16* rb = kh + w * 2048;
        #pragma unroll
        for (int j = 0; j < 4; ++j) {
            const int tcgl = j >> 1;
            const int jj   = j & 1;
            #pragma unroll
            for (int rr = 0; rr < 4; ++rr) {
                const float rv = acc[j][rr];
                const _Float16 hi = (_Float16)rv;
                const _Float16 lo = (_Float16)(rv - (float)hi);
                const int elem = ((l4 * 4 + rr) + 16 * (2 * jj + (l15 >> 3))) * 8
                               + (l15 & 7);
                rb[tcgl * 1024 + elem]       = hi;
                rb[tcgl * 1024 + 512 + elem] = lo;
            }
        }
        const int sb = (s0 >> 4) + w;
        const size_t hb = (size_t)bh << 16;
        #pragma unroll
        for (int tcgl = 0; tcgl < 2; ++tcgl) {
            const f16x8 ph = *(const f16x8*)&rb[tcgl * 1024 + l * 8];
            const f16x8 pl = *(const f16x8*)&rb[tcgl * 1024 + 512 + l * 8];
            const size_t oi = hb + (size_t)sb * 4096
                            + (size_t)((t0 >> 5) + tcgl) * 512 + l * 8;
            *(f16x8*)&r_hi[oi] = ph;
            *(f16x8*)&r_lo[oi] = pl;
        }
    } else {
        // ================= VSPLIT role (2-way fp16, hoisted loads) =========
        float (*tile)[257] = (float(*)[257])lds_arena;   // 32 x 257 fp32 (33 KB)

        const int vi = trio;                  // [0, nbh*8)
        const int bh = vi >> 3;
        const int tc = vi & 7;

        const float* vb = v + (size_t)bh * S * S + (size_t)tc * 32 * S;
        {
            const int c4 = (tid & 63) * 4;
            const int r  = tid >> 6;
            float4 vf[8];
            #pragma unroll
            for (int rr = 0; rr < 8; ++rr)
                vf[rr] = *(const float4*)&vb[(size_t)(rr * 4 + r) * S + c4];
            #pragma unroll
            for (int rr = 0; rr < 8; ++rr) {
                const int row = rr * 4 + r;
                tile[row][c4 + 0] = vf[rr].x; tile[row][c4 + 1] = vf[rr].y;
                tile[row][c4 + 2] = vf[rr].z; tile[row][c4 + 3] = vf[rr].w;
            }
        }
        __syncthreads();

        const size_t obase = (size_t)bh * S * S + (size_t)tc * 8192;
        #pragma unroll
        for (int it = 0; it < 4; ++it) {
            const int id  = it * 256 + tid;      // 0..1023
            const int j   = id >> 6;
            const int l4  = (id >> 4) & 3;
            const int l15 = id & 15;
            const int d   = j * 16 + l15;
            const int t0  = l4 * 8;
            f16x8 hv, lv;
            #pragma unroll
            for (int e = 0; e < 8; ++e) {
                const float x = tile[t0 + e][d];
                const _Float16 hi = (_Float16)x;
                hv[e] = hi; lv[e] = (_Float16)(x - (float)hi);
            }
            const size_t oi = obase + (size_t)id * 8;
            *(f16x8*)&vth[oi] = hv;
            *(f16x8*)&vtl[oi] = lv;
        }
    }
}

// ===== attn2 (verified r19/r21): fp16 2-way splits, 64 KB arena, setprio =====
#define SRC_OF(sp) ((sp) == 0 ? vth : vtl)

#define P2_LOAD(tc)                                                           \
    _Pragma("unroll")                                                         \
    for (int r_ = 0; r_ < 8; ++r_) {                                          \
        const int sp_ = r_ >> 2, qt_ = r_ & 3;                                \
        const _Float16* s_ = SRC_OF(sp_);                                     \
        stg[r_] = *(const f16x8*)&s_[hb + (size_t)(tc) * 8192 + qt_ * 2048 + tid * 8]; \
    }

#define P2_WRITE()                                                            \
    _Pragma("unroll")                                                         \
    for (int r_ = 0; r_ < 8; ++r_) {                                          \
        const int sp_ = r_ >> 2, qt_ = r_ & 3;                                \
        *(f16x8*)&arena[sp_ * 8192 + qt_ * 2048 + tid * 8] = stg[r_];         \
    }

#define P3_LOAD(tc)                                                           \
    _Pragma("unroll")                                                         \
    for (int r_ = 0; r_ < 8; ++r_) {                                          \
        const int sp_ = r_ >> 2, qt_ = r_ & 3;                                \
        const _Float16* s_ = SRC_OF(sp_);                                     \
        stg[r_] = *(const f16x8*)&s_[hb + (size_t)(tc) * 8192 + qt_ * 2048 + tid * 8]; \
    }

#define P3_WRITE()                                                            \
    _Pragma("unroll")                                                         \
    for (int r_ = 0; r_ < 8; ++r_) {                                          \
        const int sp_ = r_ >> 2, qt_ = r_ & 3;                                \
        *(f16x8*)&arena[16384 + sp_ * 8192 + qt_ * 2048 + tid * 8] = stg[r_]; \
    }

__global__ __launch_bounds__(NT, 2) void attn2_kernel(
    const float* __restrict__ mask,
    const _Float16* __restrict__ r_hi, const _Float16* __restrict__ r_lo,
    const _Float16* __restrict__ vth, const _Float16* __restrict__ vtl,
    float* __restrict__ out, int H, int swz)
{
    __shared__ __align__(16) _Float16 arena[32768];   // 64 KB

    const int tid = threadIdx.x;
    const int w = tid >> 6, l = tid & 63, l15 = l & 15, l4 = l >> 4;

    int L = blockIdx.x;
    if (swz) L = (blockIdx.x & 7) * ((int)gridDim.x >> 3) + (blockIdx.x >> 3);
    const int bh = L >> 2;
    const int s0 = (L & 3) << 6;
    const int h  = bh % H;

    const size_t hb = (size_t)bh << 16;
    const float* mbase = mask + ((size_t)h << 16);

    const int sb_a = (s0 >> 4) + w;
    const _Float16* rh_p = r_hi + hb + (size_t)sb_a * 4096;  // packed, + tc*512 + l*8
    const _Float16* rl_p = r_lo + hb + (size_t)sb_a * 4096;
    const float*    m_p  = mbase + (size_t)(s0 + 16 * w + l15) * S;

    f16x8 stg[8];

    // ---- phase 2: acc2 = (mask + r) @ V ----
    f32x4 acc2[16];
    #pragma unroll
    for (int j = 0; j < 16; ++j) acc2[j] = (f32x4){0.f, 0.f, 0.f, 0.f};

    P2_LOAD(0);
    P2_WRITE();
    P2_LOAD(1);
    f16x8 rhc, rlc; float4 m0c, m1c;
    {
        rhc = *(const f16x8*)&rh_p[l * 8];
        rlc = *(const f16x8*)&rl_p[l * 8];
        m0c = *(const float4*)&m_p[l4 * 8];
        m1c = *(const float4*)&m_p[l4 * 8 + 4];
    }
    __syncthreads();

    #pragma unroll
    for (int tc = 0; tc < 8; ++tc) {
        f16x8 rhn, rln; float4 m0n, m1n;
        if (tc < 7) {
            rhn = *(const f16x8*)&rh_p[(tc + 1) * 512 + l * 8];
            rln = *(const f16x8*)&rl_p[(tc + 1) * 512 + l * 8];
            const int ko_ = (tc + 1) * 32 + l4 * 8;
            m0n = *(const float4*)&m_p[ko_];
            m1n = *(const float4*)&m_p[ko_ + 4];
        }
        f16x8 mf;
        mf[0] = (_Float16)m0c.x; mf[1] = (_Float16)m0c.y;
        mf[2] = (_Float16)m0c.z; mf[3] = (_Float16)m0c.w;
        mf[4] = (_Float16)m1c.x; mf[5] = (_Float16)m1c.y;
        mf[6] = (_Float16)m1c.z; mf[7] = (_Float16)m1c.w;

        __builtin_amdgcn_s_setprio(1);
        #pragma unroll
        for (int j = 0; j < 16; ++j) {
            const int fo = j * 512 + l * 8;      // lane-linear, conflict-free
            const f16x8 vh = *(const f16x8*)&arena[fo];
            const f16x8 vl = *(const f16x8*)&arena[8192 + fo];
            acc2[j] = MFMA(mf,  vh, acc2[j]);
            acc2[j] = MFMA(mf,  vl, acc2[j]);
            acc2[j] = MFMA(rhc, vh, acc2[j]);
            acc2[j] = MFMA(rhc, vl, acc2[j]);
            acc2[j] = MFMA(rlc, vh, acc2[j]);
        }
        __builtin_amdgcn_s_setprio(0);
        __syncthreads();
        if (tc < 7) {
            P2_WRITE();
            if (tc < 6) P2_LOAD(tc + 2);
            rhc = rhn; rlc = rln; m0c = m0n; m1c = m1n;
            __syncthreads();
        }
    }

    P3_LOAD(0);

    // ---- masked fill + row softmax (in-register, per 16-lane group) ----
    #pragma unroll
    for (int rr = 0; rr < 4; ++rr) {
        const int srow = 16 * w + l4 * 4 + rr;
        const float* mrow = mbase + (size_t)(s0 + srow) * S;
        float mx = -3.4e38f;
        #pragma unroll
        for (int j = 0; j < 16; ++j) {
            const float mval = mrow[j * 16 + l15];
            const float a = (mval == 0.0f) ? -1e9f : acc2[j][rr];
            acc2[j][rr] = a;
            mx = fmaxf(mx, a);
        }
        #pragma unroll
        for (int off = 1; off < 16; off <<= 1)
            mx = fmaxf(mx, __shfl_xor(mx, off, 64));
        float sm = 0.f;
        #pragma unroll
        for (int j = 0; j < 16; ++j) {
            const float e = __expf(acc2[j][rr] - mx);
            acc2[j][rr] = e;
            sm += e;
        }
        #pragma unroll
        for (int off = 1; off < 16; off <<= 1)
            sm += __shfl_xor(sm, off, 64);
        const float inv = 1.0f / sm;
        #pragma unroll
        for (int j = 0; j < 16; ++j) {
            const int t = j * 16 + l15;
            arena[((srow << 8) + t) ^ ((srow & 7) << 3)] = (_Float16)(acc2[j][rr] * inv);
        }
    }
    P3_WRITE();
    P3_LOAD(1);
    __syncthreads();

    // ---- phase 3: out = P @ V ----
    f32x4 acc3[16];
    #pragma unroll
    for (int j = 0; j < 16; ++j) acc3[j] = (f32x4){0.f, 0.f, 0.f, 0.f};

    const int prow = 16 * w + l15;
    #pragma unroll
    for (int tc = 0; tc < 8; ++tc) {
        const int pb = ((prow << 8) + tc * 32 + l4 * 8) ^ ((prow & 7) << 3);
        const f16x8 pa = *(const f16x8*)&arena[pb];
        __builtin_amdgcn_s_setprio(1);
        #pragma unroll
        for (int j = 0; j < 16; ++j) {
            const int fo = 16384 + j * 512 + l * 8;
            acc3[j] = MFMA(pa, *(const f16x8*)&arena[fo], acc3[j]);
            acc3[j] = MFMA(pa, *(const f16x8*)&arena[8192 + fo], acc3[j]);
        }
        __builtin_amdgcn_s_setprio(0);
        __syncthreads();
        if (tc < 7) {
            P3_WRITE();
            if (tc < 6) P3_LOAD(tc + 2);
            __syncthreads();
        }
    }

    float* ob = out + hb + (size_t)s0 * S;
    #pragma unroll
    for (int j = 0; j < 16; ++j) {
        #pragma unroll
        for (int rr = 0; rr < 4; ++rr)
            ob[(size_t)(16 * w + l4 * 4 + rr) * S + j * 16 + l15] = acc3[j][rr];
    }
}

// ================= fallback: fp32 path (verified round 2) =================
__global__ __launch_bounds__(NT) void transpose_k_kernel(
    const float* __restrict__ k, float* __restrict__ kt)
{
    __shared__ float tile[64][65];
    const int tileIdx = blockIdx.x & 15;
    const int bh      = blockIdx.x >> 4;
    const int ti = (tileIdx >> 2) * 64;
    const int tj = (tileIdx & 3) * 64;
    const float* kb = k  + (size_t)bh * S * S;
    float*      ktb = kt + (size_t)bh * S * S;
    const int c  = threadIdx.x & 63;
    const int r4 = threadIdx.x >> 6;
    #pragma unroll
    for (int rr = 0; rr < 64; rr += 4)
        tile[rr + r4][c] = kb[(size_t)(ti + rr + r4) * S + tj + c];
    __syncthreads();
    #pragma unroll
    for (int rr = 0; rr < 64; rr += 4)
        ktb[(size_t)(tj + rr + r4) * S + ti + c] = tile[c][rr + r4];
}

template <int RPB>
__global__ __launch_bounds__(NT) void fused_attn_rpb(
    const float* __restrict__ q, const float* __restrict__ kt,
    const float* __restrict__ v, const float* __restrict__ mask,
    float* __restrict__ out, int nbh, int H, int swizzle)
{
    __shared__ float qT[S][RPB];
    __shared__ float sT[S][RPB];
    __shared__ float redbuf[4][RPB];

    const int tid = threadIdx.x;
    constexpr int NRB = S / RPB;
    int bh, rb;
    if (swizzle) {
        const int xcd  = blockIdx.x & 7;
        const int slot = blockIdx.x >> 3;
        const int hpx  = nbh >> 3;
        bh = xcd * hpx + (slot % hpx);
        rb = slot / hpx;
    } else {
        bh = blockIdx.x / NRB;
        rb = blockIdx.x % NRB;
    }
    const int h  = bh % H;
    const int s0 = rb * RPB;

    const float* qb  = q    + (size_t)bh * S * S;
    const float* ktb = kt   + (size_t)bh * S * S;
    const float* vb  = v    + (size_t)bh * S * S;
    const float* mb  = mask + (size_t)h  * S * S + (size_t)s0 * S;
    float*       ob  = out  + (size_t)bh * S * S + (size_t)s0 * S;

    #pragma unroll
    for (int si = 0; si < RPB; ++si)
        qT[tid][si] = qb[(size_t)(s0 + si) * S + tid];
    __syncthreads();

    {
        float acc[RPB];
        #pragma unroll
        for (int si = 0; si < RPB; ++si) acc[si] = 0.f;
        #pragma unroll 4
        for (int i = 0; i < S; ++i) {
            const float kv = ktb[(size_t)i * S + tid];
            #pragma unroll
            for (int si4 = 0; si4 < RPB; si4 += 4) {
                const float4 qa = *reinterpret_cast<const float4*>(&qT[i][si4]);
                acc[si4+0] = fmaf(qa.x, kv, acc[si4+0]);
                acc[si4+1] = fmaf(qa.y, kv, acc[si4+1]);
                acc[si4+2] = fmaf(qa.z, kv, acc[si4+2]);
                acc[si4+3] = fmaf(qa.w, kv, acc[si4+3]);
            }
        }
        #pragma unroll
        for (int si4 = 0; si4 < RPB; si4 += 4) {
            float4 t4;
            t4.x = fmaf(acc[si4+0], SCALE, mb[(size_t)(si4+0)*S + tid]);
            t4.y = fmaf(acc[si4+1], SCALE, mb[(size_t)(si4+1)*S + tid]);
            t4.z = fmaf(acc[si4+2], SCALE, mb[(size_t)(si4+2)*S + tid]);
            t4.w = fmaf(acc[si4+3], SCALE, mb[(size_t)(si4+3)*S + tid]);
            *reinterpret_cast<float4*>(&sT[tid][si4]) = t4;
        }
    }
    __syncthreads();

    float a1[RPB];
    #pragma unroll
    for (int si = 0; si < RPB; ++si) a1[si] = 0.f;
    #pragma unroll 2
    for (int t = 0; t < S; ++t) {
        const float vv = vb[(size_t)t * S + tid];
        #pragma unroll
        for (int si4 = 0; si4 < RPB; si4 += 4) {
            const float4 pa = *reinterpret_cast<const float4*>(&sT[t][si4]);
            a1[si4+0] = fmaf(pa.x, vv, a1[si4+0]);
            a1[si4+1] = fmaf(pa.y, vv, a1[si4+1]);
            a1[si4+2] = fmaf(pa.z, vv, a1[si4+2]);
            a1[si4+3] = fmaf(pa.w, vv, a1[si4+3]);
        }
    }
    #pragma unroll
    for (int si = 0; si < RPB; ++si)
        if (mb[(size_t)si * S + tid] == 0.0f) a1[si] = -1e9f;

    const int lane = tid & 63;
    const int wv   = tid >> 6;
    #pragma unroll
    for (int si = 0; si < RPB; ++si) {
        float m = a1[si];
        #pragma unroll
        for (int off = 32; off > 0; off >>= 1)
            m = fmaxf(m, __shfl_down(m, off, 64));
        if (lane == 0) redbuf[wv][si] = m;
    }
    __syncthreads();
    float e[RPB];
    #pragma unroll
    for (int si = 0; si < RPB; ++si) {
        const float m = fmaxf(fmaxf(redbuf[0][si], redbuf[1][si]),
                              fmaxf(redbuf[2][si], redbuf[3][si]));
        e[si] = __expf(a1[si] - m);
    }
    __syncthreads();
    #pragma unroll
    for (int si = 0; si < RPB; ++si) {
        float sm = e[si];
        #pragma unroll
        for (int off = 32; off > 0; off >>= 1)
            sm += __shfl_down(sm, off, 64);
        if (lane == 0) redbuf[wv][si] = sm;
    }
    __syncthreads();
    #pragma unroll
    for (int si4 = 0; si4 < RPB; si4 += 4) {
        float4 t4;
        #pragma unroll
        for (int jj = 0; jj < 4; ++jj) {
            const int si = si4 + jj;
            const float sm = redbuf[0][si] + redbuf[1][si] +
                             redbuf[2][si] + redbuf[3][si];
            (&t4.x)[jj] = e[si] / sm;
        }
        *reinterpret_cast<float4*>(&sT[tid][si4]) = t4;
    }
    __syncthreads();

    float o[RPB];
    #pragma unroll
    for (int si = 0; si < RPB; ++si) o[si] = 0.f;
    #pragma unroll 2
    for (int t = 0; t < S; ++t) {
        const float vv = vb[(size_t)t * S + tid];
        #pragma unroll
        for (int si4 = 0; si4 < RPB; si4 += 4) {
            const float4 pa = *reinterpret_cast<const float4*>(&sT[t][si4]);
            o[si4+0] = fmaf(pa.x, vv, o[si4+0]);
            o[si4+1] = fmaf(pa.y, vv, o[si4+1]);
            o[si4+2] = fmaf(pa.z, vv, o[si4+2]);
            o[si4+3] = fmaf(pa.w, vv, o[si4+3]);
        }
    }
    #pragma unroll
    for (int si = 0; si < RPB; ++si)
        ob[(size_t)si * S + tid] = o[si];
}

extern "C" void kernel_launch(void* const* d_in, const int* in_sizes, int n_in,
                              void* d_out, int out_size, void* d_ws, size_t ws_size,
                              hipStream_t stream) {
    const float* q    = (const float*)d_in[0];
    const float* k    = (const float*)d_in[1];
    const float* v    = (const float*)d_in[2];
    const float* mask = (const float*)d_in[3];
    float* out = (float*)d_out;

    const int nbh = in_sizes[0] / (S * S);   // B*H
    const int H   = in_sizes[3] / (S * S);   // heads
    const size_t he = (size_t)nbh * S * S;
    const size_t need = he * sizeof(_Float16) * 4;   // vth,vtl,r_hi,r_lo
    const size_t kt_bytes = he * sizeof(float);

    if (ws_size >= need) {
        _Float16* vth = (_Float16*)d_ws;
        _Float16* vtl = vth + he;
        _Float16* rhi = vtl + he;
        _Float16* rlo = rhi + he;
        const int nblk_q = nbh * 16;
        const int nblk_a = nbh * 4;
        const int swzq = (nblk_q % 8 == 0) ? 1 : 0;
        const int swza = (nblk_a % 8 == 0) ? 1 : 0;
        prep_kernel<<<dim3(nbh * 24), NT, 0, stream>>>(
            q, k, v, vth, vtl, rhi, rlo, nbh, swzq);
        attn2_kernel<<<dim3(nblk_a), NT, 0, stream>>>(
            mask, rhi, rlo, vth, vtl, out, H, swza);
    } else if (ws_size >= kt_bytes) {
        float* kt = (float*)d_ws;
        transpose_k_kernel<<<dim3(nbh * 16), NT, 0, stream>>>(k, kt);
        constexpr int RPB = 16;
        const int grid = nbh * (S / RPB);
        const int swz = (nbh % 8 == 0) ? 1 : 0;
        fused_attn_rpb<RPB><<<dim3(grid), NT, 0, stream>>>(
            q, kt, v, mask, out, nbh, H, swz);
    }
}

// Round 23
// 78.820 us; speedup vs baseline: 1.0340x; 1.0340x over previous
//
#include <hip/hip_runtime.h>
#include <math.h>

namespace {
constexpr int S  = 256;
constexpr int NT = 256;
constexpr float SCALE = 0.0625f;  // 1/sqrt(256)
constexpr int KLD = 264;          // qkt LDS row stride (f16): 256 + 8 pad
}

typedef _Float16 f16x4 __attribute__((ext_vector_type(4)));
typedef _Float16 f16x8 __attribute__((ext_vector_type(8)));
typedef float    f32x4 __attribute__((ext_vector_type(4)));

#define MFMA(a, b, c) __builtin_amdgcn_mfma_f32_16x16x32_f16((a), (b), (c), 0, 0, 0)

// ===== prep (verified r21): fused {qkt 64s x 64t, vsplit} — %3 roles,
// hoisted staging loads. All splits 2-way fp16 (hi/lo ~ fp32).
// packed r idx = sb*4096 + tcg*512 + lane*8 + e
__global__ __launch_bounds__(NT, 2) void prep_kernel(
    const float* __restrict__ q, const float* __restrict__ k,
    const float* __restrict__ v,
    _Float16* __restrict__ vth, _Float16* __restrict__ vtl,
    _Float16* __restrict__ r_hi, _Float16* __restrict__ r_lo,
    int nbh, int swzq)
{
    __shared__ __align__(16) unsigned char lds_arena[64 * KLD * 2 * 2];  // 67.6 KB

    const int tid  = threadIdx.x;
    const int trio = blockIdx.x / 3;
    const int role = blockIdx.x % 3;

    if (role < 2) {
        // ================= QKT role: 64s x 64t =================
        _Float16* kh = (_Float16*)lds_arena;
        _Float16* kl = kh + 64 * KLD;

        const int w = tid >> 6, l = tid & 63, l15 = l & 15, l4 = l >> 4;

        int L = trio * 2 + role;                 // [0, nbh*16)
        if (swzq) {
            const int n = nbh * 16;
            L = (L & 7) * (n >> 3) + (L >> 3);
        }
        const int bh = L >> 4;
        const int s0 = ((L >> 2) & 3) << 6;
        const int t0 = (L & 3) << 6;

        const float* qb = q + ((size_t)bh << 16);
        const float* kb = k + ((size_t)bh << 16);

        // stage K tile [t0, t0+64) x 256: ALL 16 loads issued first (hoisted),
        // then convert+write — one HBM latency exposure instead of four.
        {
            const float* ksrc = kb + (size_t)t0 * S;    // 64 KB contiguous
            float4 kf[16];
            #pragma unroll
            for (int it = 0; it < 16; ++it)
                kf[it] = *(const float4*)&ksrc[it * 1024 + tid * 4];
            #pragma unroll
            for (int it = 0; it < 16; ++it) {
                const int idx = it * 1024 + tid * 4;
                const float xs[4] = {kf[it].x, kf[it].y, kf[it].z, kf[it].w};
                f16x4 hv, lv;
                #pragma unroll
                for (int e = 0; e < 4; ++e) {
                    const _Float16 hi = (_Float16)xs[e];
                    hv[e] = hi; lv[e] = (_Float16)(xs[e] - (float)hi);
                }
                const int row = idx >> 8;
                const int col = idx & 255;
                *(f16x4*)&kh[row * KLD + col] = hv;
                *(f16x4*)&kl[row * KLD + col] = lv;
            }
        }

        // Q rows, pre-scaled, hi/lo fp16 split (loads hoisted)
        f16x8 qh[8], ql[8];
        {
            const float* qr = qb + (size_t)(s0 + 16 * w + l15) * S;
            float4 qf[16];
            #pragma unroll
            for (int kc = 0; kc < 8; ++kc) {
                qf[2 * kc]     = *(const float4*)&qr[kc * 32 + l4 * 8];
                qf[2 * kc + 1] = *(const float4*)&qr[kc * 32 + l4 * 8 + 4];
            }
            #pragma unroll
            for (int kc = 0; kc < 8; ++kc) {
                const float xs[8] = {qf[2*kc].x, qf[2*kc].y, qf[2*kc].z, qf[2*kc].w,
                                     qf[2*kc+1].x, qf[2*kc+1].y, qf[2*kc+1].z, qf[2*kc+1].w};
                f16x8 hv, lv;
                #pragma unroll
                for (int e = 0; e < 8; ++e) {
                    const float x = xs[e] * SCALE;
                    const _Float16 hi = (_Float16)x;
                    hv[e] = hi; lv[e] = (_Float16)(x - (float)hi);
                }
                qh[kc] = hv; ql[kc] = lv;
            }
        }
        __syncthreads();

        f32x4 acc[4];
        #pragma unroll
        for (int j = 0; j < 4; ++j) acc[j] = (f32x4){0.f, 0.f, 0.f, 0.f};

        #pragma unroll
        for (int kc = 0; kc < 8; ++kc) {
            #pragma unroll
            for (int j = 0; j < 4; ++j) {
                const int bo = (j * 16 + l15) * KLD + kc * 32 + l4 * 8;
                const f16x8 khf = *(const f16x8*)&kh[bo];
                const f16x8 klf = *(const f16x8*)&kl[bo];
                acc[j] = MFMA(qh[kc], khf, acc[j]);
                acc[j] = MFMA(qh[kc], klf, acc[j]);
                acc[j] = MFMA(ql[kc], khf, acc[j]);
            }
        }
        __syncthreads();   // all waves done with kh/kl -> reuse kh as bounce

        // ---- packed epilogue via per-wave LDS bounce (4 KB/wave in kh) ----
        _Float16* rb = kh + w * 2048;
        #pragma unroll
        for (int j = 0; j < 4; ++j) {
            const int tcgl = j >> 1;
            const int jj   = j & 1;
            #pragma unroll
            for (int rr = 0; rr < 4; ++rr) {
                const float rv = acc[j][rr];
                const _Float16 hi = (_Float16)rv;
                const _Float16 lo = (_Float16)(rv - (float)hi);
                const int elem = ((l4 * 4 + rr) + 16 * (2 * jj + (l15 >> 3))) * 8
                               + (l15 & 7);
                rb[tcgl * 1024 + elem]       = hi;
                rb[tcgl * 1024 + 512 + elem] = lo;
            }
        }
        const int sb = (s0 >> 4) + w;
        const size_t hb = (size_t)bh << 16;
        #pragma unroll
        for (int tcgl = 0; tcgl < 2; ++tcgl) {
            const f16x8 ph = *(const f16x8*)&rb[tcgl * 1024 + l * 8];
            const f16x8 pl = *(const f16x8*)&rb[tcgl * 1024 + 512 + l * 8];
            const size_t oi = hb + (size_t)sb * 4096
                            + (size_t)((t0 >> 5) + tcgl) * 512 + l * 8;
            *(f16x8*)&r_hi[oi] = ph;
            *(f16x8*)&r_lo[oi] = pl;
        }
    } else {
        // ================= VSPLIT role (2-way fp16, hoisted loads) =========
        float (*tile)[257] = (float(*)[257])lds_arena;   // 32 x 257 fp32 (33 KB)

        const int vi = trio;                  // [0, nbh*8)
        const int bh = vi >> 3;
        const int tc = vi & 7;

        const float* vb = v + (size_t)bh * S * S + (size_t)tc * 32 * S;
        {
            const int c4 = (tid & 63) * 4;
            const int r  = tid >> 6;
            float4 vf[8];
            #pragma unroll
            for (int rr = 0; rr < 8; ++rr)
                vf[rr] = *(const float4*)&vb[(size_t)(rr * 4 + r) * S + c4];
            #pragma unroll
            for (int rr = 0; rr < 8; ++rr) {
                const int row = rr * 4 + r;
                tile[row][c4 + 0] = vf[rr].x; tile[row][c4 + 1] = vf[rr].y;
                tile[row][c4 + 2] = vf[rr].z; tile[row][c4 + 3] = vf[rr].w;
            }
        }
        __syncthreads();

        const size_t obase = (size_t)bh * S * S + (size_t)tc * 8192;
        #pragma unroll
        for (int it = 0; it < 4; ++it) {
            const int id  = it * 256 + tid;      // 0..1023
            const int j   = id >> 6;
            const int l4  = (id >> 4) & 3;
            const int l15 = id & 15;
            const int d   = j * 16 + l15;
            const int t0  = l4 * 8;
            f16x8 hv, lv;
            #pragma unroll
            for (int e = 0; e < 8; ++e) {
                const float x = tile[t0 + e][d];
                const _Float16 hi = (_Float16)x;
                hv[e] = hi; lv[e] = (_Float16)(x - (float)hi);
            }
            const size_t oi = obase + (size_t)id * 8;
            *(f16x8*)&vth[oi] = hv;
            *(f16x8*)&vtl[oi] = lv;
        }
    }
}

// ===== attn2 (verified r19/r21): fp16 2-way splits, 64 KB arena, setprio =====
#define SRC_OF(sp) ((sp) == 0 ? vth : vtl)

#define P2_LOAD(tc)                                                           \
    _Pragma("unroll")                                                         \
    for (int r_ = 0; r_ < 8; ++r_) {                                          \
        const int sp_ = r_ >> 2, qt_ = r_ & 3;                                \
        const _Float16* s_ = SRC_OF(sp_);                                     \
        stg[r_] = *(const f16x8*)&s_[hb + (size_t)(tc) * 8192 + qt_ * 2048 + tid * 8]; \
    }

#define P2_WRITE()                                                            \
    _Pragma("unroll")                                                         \
    for (int r_ = 0; r_ < 8; ++r_) {                                          \
        const int sp_ = r_ >> 2, qt_ = r_ & 3;                                \
        *(f16x8*)&arena[sp_ * 8192 + qt_ * 2048 + tid * 8] = stg[r_];         \
    }

#define P3_LOAD(tc)                                                           \
    _Pragma("unroll")                                                         \
    for (int r_ = 0; r_ < 8; ++r_) {                                          \
        const int sp_ = r_ >> 2, qt_ = r_ & 3;                                \
        const _Float16* s_ = SRC_OF(sp_);                                     \
        stg[r_] = *(const f16x8*)&s_[hb + (size_t)(tc) * 8192 + qt_ * 2048 + tid * 8]; \
    }

#define P3_WRITE()                                                            \
    _Pragma("unroll")                                                         \
    for (int r_ = 0; r_ < 8; ++r_) {                                          \
        const int sp_ = r_ >> 2, qt_ = r_ & 3;                                \
        *(f16x8*)&arena[16384 + sp_ * 8192 + qt_ * 2048 + tid * 8] = stg[r_]; \
    }

__global__ __launch_bounds__(NT, 2) void attn2_kernel(
    const float* __restrict__ mask,
    const _Float16* __restrict__ r_hi, const _Float16* __restrict__ r_lo,
    const _Float16* __restrict__ vth, const _Float16* __restrict__ vtl,
    float* __restrict__ out, int H, int swz)
{
    __shared__ __align__(16) _Float16 arena[32768];   // 64 KB

    const int tid = threadIdx.x;
    const int w = tid >> 6, l = tid & 63, l15 = l & 15, l4 = l >> 4;

    int L = blockIdx.x;
    if (swz) L = (blockIdx.x & 7) * ((int)gridDim.x >> 3) + (blockIdx.x >> 3);
    const int bh = L >> 2;
    const int s0 = (L & 3) << 6;
    const int h  = bh % H;

    const size_t hb = (size_t)bh << 16;
    const float* mbase = mask + ((size_t)h << 16);

    const int sb_a = (s0 >> 4) + w;
    const _Float16* rh_p = r_hi + hb + (size_t)sb_a * 4096;  // packed, + tc*512 + l*8
    const _Float16* rl_p = r_lo + hb + (size_t)sb_a * 4096;
    const float*    m_p  = mbase + (size_t)(s0 + 16 * w + l15) * S;

    f16x8 stg[8];

    // ---- phase 2: acc2 = (mask + r) @ V ----
    f32x4 acc2[16];
    #pragma unroll
    for (int j = 0; j < 16; ++j) acc2[j] = (f32x4){0.f, 0.f, 0.f, 0.f};

    P2_LOAD(0);
    P2_WRITE();
    P2_LOAD(1);
    f16x8 rhc, rlc; float4 m0c, m1c;
    {
        rhc = *(const f16x8*)&rh_p[l * 8];
        rlc = *(const f16x8*)&rl_p[l * 8];
        m0c = *(const float4*)&m_p[l4 * 8];
        m1c = *(const float4*)&m_p[l4 * 8 + 4];
    }
    __syncthreads();

    #pragma unroll
    for (int tc = 0; tc < 8; ++tc) {
        f16x8 rhn, rln; float4 m0n, m1n;
        if (tc < 7) {
            rhn = *(const f16x8*)&rh_p[(tc + 1) * 512 + l * 8];
            rln = *(const f16x8*)&rl_p[(tc + 1) * 512 + l * 8];
            const int ko_ = (tc + 1) * 32 + l4 * 8;
            m0n = *(const float4*)&m_p[ko_];
            m1n = *(const float4*)&m_p[ko_ + 4];
        }
        f16x8 mf;
        mf[0] = (_Float16)m0c.x; mf[1] = (_Float16)m0c.y;
        mf[2] = (_Float16)m0c.z; mf[3] = (_Float16)m0c.w;
        mf[4] = (_Float16)m1c.x; mf[5] = (_Float16)m1c.y;
        mf[6] = (_Float16)m1c.z; mf[7] = (_Float16)m1c.w;

        __builtin_amdgcn_s_setprio(1);
        #pragma unroll
        for (int j = 0; j < 16; ++j) {
            const int fo = j * 512 + l * 8;      // lane-linear, conflict-free
            const f16x8 vh = *(const f16x8*)&arena[fo];
            const f16x8 vl = *(const f16x8*)&arena[8192 + fo];
            acc2[j] = MFMA(mf,  vh, acc2[j]);
            acc2[j] = MFMA(mf,  vl, acc2[j]);
            acc2[j] = MFMA(rhc, vh, acc2[j]);
            acc2[j] = MFMA(rhc, vl, acc2[j]);
            acc2[j] = MFMA(rlc, vh, acc2[j]);
        }
        __builtin_amdgcn_s_setprio(0);
        __syncthreads();
        if (tc < 7) {
            P2_WRITE();
            if (tc < 6) P2_LOAD(tc + 2);
            rhc = rhn; rlc = rln; m0c = m0n; m1c = m1n;
            __syncthreads();
        }
    }

    P3_LOAD(0);

    // ---- masked fill + row softmax (in-register, per 16-lane group) ----
    #pragma unroll
    for (int rr = 0; rr < 4; ++rr) {
        const int srow = 16 * w + l4 * 4 + rr;
        const float* mrow = mbase + (size_t)(s0 + srow) * S;
        float mx = -3.4e38f;
        #pragma unroll
        for (int j = 0; j < 16; ++j) {
            const float mval = mrow[j * 16 + l15];
            const float a = (mval == 0.0f) ? -1e9f : acc2[j][rr];
            acc2[j][rr] = a;
            mx = fmaxf(mx, a);
        }
        #pragma unroll
        for (int off = 1; off < 16; off <<= 1)
            mx = fmaxf(mx, __shfl_xor(mx, off, 64));
        float sm = 0.f;
        #pragma unroll
        for (int j = 0; j < 16; ++j) {
            const float e = __expf(acc2[j][rr] - mx);
            acc2[j][rr] = e;
            sm += e;
        }
        #pragma unroll
        for (int off = 1; off < 16; off <<= 1)
            sm += __shfl_xor(sm, off, 64);
        const float inv = 1.0f / sm;
        #pragma unroll
        for (int j = 0; j < 16; ++j) {
            const int t = j * 16 + l15;
            arena[((srow << 8) + t) ^ ((srow & 7) << 3)] = (_Float16)(acc2[j][rr] * inv);
        }
    }
    P3_WRITE();
    P3_LOAD(1);
    __syncthreads();

    // ---- phase 3: out = P @ V ----
    f32x4 acc3[16];
    #pragma unroll
    for (int j = 0; j < 16; ++j) acc3[j] = (f32x4){0.f, 0.f, 0.f, 0.f};

    const int prow = 16 * w + l15;
    #pragma unroll
    for (int tc = 0; tc < 8; ++tc) {
        const int pb = ((prow << 8) + tc * 32 + l4 * 8) ^ ((prow & 7) << 3);
        const f16x8 pa = *(const f16x8*)&arena[pb];
        __builtin_amdgcn_s_setprio(1);
        #pragma unroll
        for (int j = 0; j < 16; ++j) {
            const int fo = 16384 + j * 512 + l * 8;
            acc3[j] = MFMA(pa, *(const f16x8*)&arena[fo], acc3[j]);
            acc3[j] = MFMA(pa, *(const f16x8*)&arena[8192 + fo], acc3[j]);
        }
        __builtin_amdgcn_s_setprio(0);
        __syncthreads();
        if (tc < 7) {
            P3_WRITE();
            if (tc < 6) P3_LOAD(tc + 2);
            __syncthreads();
        }
    }

    float* ob = out + hb + (size_t)s0 * S;
    #pragma unroll
    for (int j = 0; j < 16; ++j) {
        #pragma unroll
        for (int rr = 0; rr < 4; ++rr)
            ob[(size_t)(16 * w + l4 * 4 + rr) * S + j * 16 + l15] = acc3[j][rr];
    }
}

// ================= fallback: fp32 path (verified round 2) =================
__global__ __launch_bounds__(NT) void transpose_k_kernel(
    const float* __restrict__ k, float* __restrict__ kt)
{
    __shared__ float tile[64][65];
    const int tileIdx = blockIdx.x & 15;
    const int bh      = blockIdx.x >> 4;
    const int ti = (tileIdx >> 2) * 64;
    const int tj = (tileIdx & 3) * 64;
    const float* kb = k  + (size_t)bh * S * S;
    float*      ktb = kt + (size_t)bh * S * S;
    const int c  = threadIdx.x & 63;
    const int r4 = threadIdx.x >> 6;
    #pragma unroll
    for (int rr = 0; rr < 64; rr += 4)
        tile[rr + r4][c] = kb[(size_t)(ti + rr + r4) * S + tj + c];
    __syncthreads();
    #pragma unroll
    for (int rr = 0; rr < 64; rr += 4)
        ktb[(size_t)(tj + rr + r4) * S + ti + c] = tile[c][rr + r4];
}

template <int RPB>
__global__ __launch_bounds__(NT) void fused_attn_rpb(
    const float* __restrict__ q, const float* __restrict__ kt,
    const float* __restrict__ v, const float* __restrict__ mask,
    float* __restrict__ out, int nbh, int H, int swizzle)
{
    __shared__ float qT[S][RPB];
    __shared__ float sT[S][RPB];
    __shared__ float redbuf[4][RPB];

    const int tid = threadIdx.x;
    constexpr int NRB = S / RPB;
    int bh, rb;
    if (swizzle) {
        const int xcd  = blockIdx.x & 7;
        const int slot = blockIdx.x >> 3;
        const int hpx  = nbh >> 3;
        bh = xcd * hpx + (slot % hpx);
        rb = slot / hpx;
    } else {
        bh = blockIdx.x / NRB;
        rb = blockIdx.x % NRB;
    }
    const int h  = bh % H;
    const int s0 = rb * RPB;

    const float* qb  = q    + (size_t)bh * S * S;
    const float* ktb = kt   + (size_t)bh * S * S;
    const float* vb  = v    + (size_t)bh * S * S;
    const float* mb  = mask + (size_t)h  * S * S + (size_t)s0 * S;
    float*       ob  = out  + (size_t)bh * S * S + (size_t)s0 * S;

    #pragma unroll
    for (int si = 0; si < RPB; ++si)
        qT[tid][si] = qb[(size_t)(s0 + si) * S + tid];
    __syncthreads();

    {
        float acc[RPB];
        #pragma unroll
        for (int si = 0; si < RPB; ++si) acc[si] = 0.f;
        #pragma unroll 4
        for (int i = 0; i < S; ++i) {
            const float kv = ktb[(size_t)i * S + tid];
            #pragma unroll
            for (int si4 = 0; si4 < RPB; si4 += 4) {
                const float4 qa = *reinterpret_cast<const float4*>(&qT[i][si4]);
                acc[si4+0] = fmaf(qa.x, kv, acc[si4+0]);
                acc[si4+1] = fmaf(qa.y, kv, acc[si4+1]);
                acc[si4+2] = fmaf(qa.z, kv, acc[si4+2]);
                acc[si4+3] = fmaf(qa.w, kv, acc[si4+3]);
            }
        }
        #pragma unroll
        for (int si4 = 0; si4 < RPB; si4 += 4) {
            float4 t4;
            t4.x = fmaf(acc[si4+0], SCALE, mb[(size_t)(si4+0)*S + tid]);
            t4.y = fmaf(acc[si4+1], SCALE, mb[(size_t)(si4+1)*S + tid]);
            t4.z = fmaf(acc[si4+2], SCALE, mb[(size_t)(si4+2)*S + tid]);
            t4.w = fmaf(acc[si4+3], SCALE, mb[(size_t)(si4+3)*S + tid]);
            *reinterpret_cast<float4*>(&sT[tid][si4]) = t4;
        }
    }
    __syncthreads();

    float a1[RPB];
    #pragma unroll
    for (int si = 0; si < RPB; ++si) a1[si] = 0.f;
    #pragma unroll 2
    for (int t = 0; t < S; ++t) {
        const float vv = vb[(size_t)t * S + tid];
        #pragma unroll
        for (int si4 = 0; si4 < RPB; si4 += 4) {
            const float4 pa = *reinterpret_cast<const float4*>(&sT[t][si4]);
            a1[si4+0] = fmaf(pa.x, vv, a1[si4+0]);
            a1[si4+1] = fmaf(pa.y, vv, a1[si4+1]);
            a1[si4+2] = fmaf(pa.z, vv, a1[si4+2]);
            a1[si4+3] = fmaf(pa.w, vv, a1[si4+3]);
        }
    }
    #pragma unroll
    for (int si = 0; si < RPB; ++si)
        if (mb[(size_t)si * S + tid] == 0.0f) a1[si] = -1e9f;

    const int lane = tid & 63;
    const int wv   = tid >> 6;
    #pragma unroll
    for (int si = 0; si < RPB; ++si) {
        float m = a1[si];
        #pragma unroll
        for (int off = 32; off > 0; off >>= 1)
            m = fmaxf(m, __shfl_down(m, off, 64));
        if (lane == 0) redbuf[wv][si] = m;
    }
    __syncthreads();
    float e[RPB];
    #pragma unroll
    for (int si = 0; si < RPB; ++si) {
        const float m = fmaxf(fmaxf(redbuf[0][si], redbuf[1][si]),
                              fmaxf(redbuf[2][si], redbuf[3][si]));
        e[si] = __expf(a1[si] - m);
    }
    __syncthreads();
    #pragma unroll
    for (int si = 0; si < RPB; ++si) {
        float sm = e[si];
        #pragma unroll
        for (int off = 32; off > 0; off >>= 1)
            sm += __shfl_down(sm, off, 64);
        if (lane == 0) redbuf[wv][si] = sm;
    }
    __syncthreads();
    #pragma unroll
    for (int si4 = 0; si4 < RPB; si4 += 4) {
        float4 t4;
        #pragma unroll
        for (int jj = 0; jj < 4; ++jj) {
            const int si = si4 + jj;
            const float sm = redbuf[0][si] + redbuf[1][si] +
                             redbuf[2][si] + redbuf[3][si];
            (&t4.x)[jj] = e[si] / sm;
        }
        *reinterpret_cast<float4*>(&sT[tid][si4]) = t4;
    }
    __syncthreads();

    float o[RPB];
    #pragma unroll
    for (int si = 0; si < RPB; ++si) o[si] = 0.f;
    #pragma unroll 2
    for (int t = 0; t < S; ++t) {
        const float vv = vb[(size_t)t * S + tid];
        #pragma unroll
        for (int si4 = 0; si4 < RPB; si4 += 4) {
            const float4 pa = *reinterpret_cast<const float4*>(&sT[t][si4]);
            o[si4+0] = fmaf(pa.x, vv, o[si4+0]);
            o[si4+1] = fmaf(pa.y, vv, o[si4+1]);
            o[si4+2] = fmaf(pa.z, vv, o[si4+2]);
            o[si4+3] = fmaf(pa.w, vv, o[si4+3]);
        }
    }
    #pragma unroll
    for (int si = 0; si < RPB; ++si)
        ob[(size_t)si * S + tid] = o[si];
}

extern "C" void kernel_launch(void* const* d_in, const int* in_sizes, int n_in,
                              void* d_out, int out_size, void* d_ws, size_t ws_size,
                              hipStream_t stream) {
    const float* q    = (const float*)d_in[0];
    const float* k    = (const float*)d_in[1];
    const float* v    = (const float*)d_in[2];
    const float* mask = (const float*)d_in[3];
    float* out = (float*)d_out;

    const int nbh = in_sizes[0] / (S * S);   // B*H
    const int H   = in_sizes[3] / (S * S);   // heads
    const size_t he = (size_t)nbh * S * S;
    const size_t need = he * sizeof(_Float16) * 4;   // vth,vtl,r_hi,r_lo
    const size_t kt_bytes = he * sizeof(float);

    if (ws_size >= need) {
        _Float16* vth = (_Float16*)d_ws;
        _Float16* vtl = vth + he;
        _Float16* rhi = vtl + he;
        _Float16* rlo = rhi + he;
        const int nblk_q = nbh * 16;
        const int nblk_a = nbh * 4;
        const int swzq = (nblk_q % 8 == 0) ? 1 : 0;
        const int swza = (nblk_a % 8 == 0) ? 1 : 0;
        prep_kernel<<<dim3(nbh * 24), NT, 0, stream>>>(
            q, k, v, vth, vtl, rhi, rlo, nbh, swzq);
        attn2_kernel<<<dim3(nblk_a), NT, 0, stream>>>(
            mask, rhi, rlo, vth, vtl, out, H, swza);
    } else if (ws_size >= kt_bytes) {
        float* kt = (float*)d_ws;
        transpose_k_kernel<<<dim3(nbh * 16), NT, 0, stream>>>(k, kt);
        constexpr int RPB = 16;
        const int grid = nbh * (S / RPB);
        const int swz = (nbh % 8 == 0) ? 1 : 0;
        fused_attn_rpb<RPB><<<dim3(grid), NT, 0, stream>>>(
            q, kt, v, mask, out, nbh, H, swz);
    }
}